// Round 4
// baseline (849.365 us; speedup 1.0000x reference)
//
#include <hip/hip_runtime.h>

#define NN 131072

struct LP {
  const float* u[12];
  int t_off[12];   // float offsets into workspace (exact-r layout)
  int r[12];
  int lb[12];      // log2(bsz) = 16 - level
};

// ---------------- t-pass ----------------
// t[seg][n][j] = sum_{s in seg} U[s][j] * x[n][s]
// grid: 12 levels * 64 chunks (2048 s each), 256 threads.
// lane = ss*16 + j4 (j4 inner 4 bits -> quarter-wave-uniform LDS x reads).
// Each lane: u rows in registers (read once from global), acc[32 n][4 j] in regs.
// Reduction: shfl (lvls 6-8), direct write (lvls 9-11), LDS+partials (lvls 0-5).
__global__ __launch_bounds__(256)
void tpass_kernel(const float* __restrict__ x, float* __restrict__ t,
                  float* __restrict__ part, LP P) {
  __shared__ float smem[8192];  // xs ping(2048) + pong(2048) + red(4096)
  const int tid = threadIdx.x;
  const int bid = blockIdx.x;
  const int l = bid >> 6;
  const int chunk = bid & 63;

  const float* __restrict__ u = P.u[l];
  const int r = P.r[l];
  const int lb = P.lb[l];
  const int r4 = r >> 2;
  float* __restrict__ tl = t + P.t_off[l];

  const int sh = 11 - lb;                                 // may be <= 0
  const int lg = (sh <= 0) ? 4 : (sh >= 4 ? 0 : 4 - sh);  // log2(strips/segment)
  const int G = 1 << lg;
  const int lips = (lg == 0 && sh > 4) ? (lb - 2) : 5;    // log2(iters/segment)
  const int ips = 1 << lips;

  const int w = tid >> 6;
  const int lane = tid & 63;
  const int j4 = lane & 15;
  const int ss = lane >> 4;
  const int p = w * 4 + ss;        // strip id 0..15
  const int cb = chunk << 11;

  float4 acc[32];
  #pragma unroll
  for (int n = 0; n < 32; n++) acc[n] = make_float4(0.f, 0.f, 0.f, 0.f);

  float* xs0 = smem;
  float* xs1 = smem + 2048;
  float* red = smem + 4096;

  const int sn = tid >> 3;   // staging n
  const int u8 = tid & 7;

  auto stage = [&](float* xs, int nit) {
    #pragma unroll
    for (int h = 0; h < 2; h++) {
      int su = u8 * 8 + h * 4;
      int rr = su >> (2 + lg);
      int seg = (sh <= 4) ? rr : ((rr << (sh - 4)) + (nit >> lips));
      int s = cb + (seg << lb) + ((nit & (ips - 1)) << (2 + lg)) + (su & (4 * G - 1));
      float4 v = *(const float4*)&x[sn * NN + s];
      int qd = (su >> 2) ^ (sn & 7);
      *(float4*)&xs[sn * 64 + qd * 4] = v;
    }
  };

  stage(xs0, 0);
  __syncthreads();

  for (int iter = 0; iter < 32; iter++) {
    if (iter + 1 < 32) stage((iter & 1) ? xs0 : xs1, iter + 1);

    // ---- u rows -> registers (read once from HBM) ----
    const int segl = (sh <= 4) ? (p >> lg) : ((p << (sh - 4)) + (iter >> lips));
    const int q = p & (G - 1);
    const int sA = cb + (segl << lb) + (((iter & (ips - 1)) * G + q) << 2);
    float4 uv0, uv1, uv2, uv3;
    if (j4 < r4) {
      const float* ub = u + (size_t)sA * r + j4 * 4;
      uv0 = *(const float4*)&ub[0];
      uv1 = *(const float4*)&ub[r];
      uv2 = *(const float4*)&ub[2 * r];
      uv3 = *(const float4*)&ub[3 * r];
    } else {
      uv0 = uv1 = uv2 = uv3 = make_float4(0.f, 0.f, 0.f, 0.f);
    }

    const float* xs = (iter & 1) ? xs1 : xs0;
    #pragma unroll
    for (int n = 0; n < 32; n++) {
      float4 xv = *(const float4*)&xs[n * 64 + ((p ^ (n & 7)) << 2)];
      acc[n].x += uv0.x * xv.x + uv1.x * xv.y + uv2.x * xv.z + uv3.x * xv.w;
      acc[n].y += uv0.y * xv.x + uv1.y * xv.y + uv2.y * xv.z + uv3.y * xv.w;
      acc[n].z += uv0.z * xv.x + uv1.z * xv.y + uv2.z * xv.z + uv3.z * xv.w;
      acc[n].w += uv0.w * xv.x + uv1.w * xv.y + uv2.w * xv.z + uv3.w * xv.w;
    }
    __syncthreads();

    if (((iter + 1) & (ips - 1)) == 0) {   // segment complete -> flush
      if (lg == 0) {
        // unique writer per segment (levels 9..11)
        if (j4 < r4) {
          int gseg = (chunk << sh) + segl;
          float* dst = tl + (size_t)gseg * 32 * r + j4 * 4;
          #pragma unroll
          for (int n = 0; n < 32; n++) *(float4*)&dst[n * r] = acc[n];
        }
        #pragma unroll
        for (int n = 0; n < 32; n++) acc[n] = make_float4(0.f, 0.f, 0.f, 0.f);
      } else if (lg <= 2) {
        // shfl reduce across 2 or 4 strips (levels 7..8, r=64)
        #pragma unroll
        for (int n = 0; n < 32; n++) {
          acc[n].x += __shfl_xor(acc[n].x, 16);
          acc[n].y += __shfl_xor(acc[n].y, 16);
          acc[n].z += __shfl_xor(acc[n].z, 16);
          acc[n].w += __shfl_xor(acc[n].w, 16);
        }
        if (lg == 2) {
          #pragma unroll
          for (int n = 0; n < 32; n++) {
            acc[n].x += __shfl_xor(acc[n].x, 32);
            acc[n].y += __shfl_xor(acc[n].y, 32);
            acc[n].z += __shfl_xor(acc[n].z, 32);
            acc[n].w += __shfl_xor(acc[n].w, 32);
          }
        }
        if ((ss & (G - 1)) == 0 && j4 < r4) {
          int gseg = (chunk << sh) + (p >> lg);
          float* dst = tl + (size_t)gseg * 32 * r + j4 * 4;
          #pragma unroll
          for (int n = 0; n < 32; n++) *(float4*)&dst[n * r] = acc[n];
        }
      } else if (lg == 3) {
        // wave-sum then cross-wave pair via LDS (level 6, r=64)
        #pragma unroll
        for (int n = 0; n < 32; n++) {
          acc[n].x += __shfl_xor(acc[n].x, 16); acc[n].y += __shfl_xor(acc[n].y, 16);
          acc[n].z += __shfl_xor(acc[n].z, 16); acc[n].w += __shfl_xor(acc[n].w, 16);
          acc[n].x += __shfl_xor(acc[n].x, 32); acc[n].y += __shfl_xor(acc[n].y, 32);
          acc[n].z += __shfl_xor(acc[n].z, 32); acc[n].w += __shfl_xor(acc[n].w, 32);
        }
        if ((w & 1) && ss == 0) {
          float* d = red + (w >> 1) * 2048 + j4 * 4;
          #pragma unroll
          for (int n = 0; n < 32; n++) *(float4*)&d[n * 64] = acc[n];
        }
        __syncthreads();
        if (!(w & 1) && ss == 0) {
          const float* sp = red + (w >> 1) * 2048 + j4 * 4;
          int gseg = (chunk << 1) + (w >> 1);
          float* dst = tl + (size_t)gseg * 2048 + j4 * 4;
          #pragma unroll
          for (int n = 0; n < 32; n++) {
            float4 b = *(const float4*)&sp[n * 64];
            float4 o = acc[n];
            o.x += b.x; o.y += b.y; o.z += b.z; o.w += b.w;
            *(float4*)&dst[n * 64] = o;
          }
        }
      } else {
        // lg==4: 16-strip LDS reduce in 8 rounds -> per-chunk partial (levels 0..5)
        for (int round = 0; round < 8; round++) {
          {
            float* d = red + p * 256 + j4 * 4;
            #pragma unroll
            for (int nn = 0; nn < 4; nn++) *(float4*)&d[nn * 64] = acc[round * 4 + nn];
          }
          __syncthreads();
          float s = 0.f;
          #pragma unroll
          for (int pp = 0; pp < 16; pp++) s += red[pp * 256 + tid];
          part[((l * 64 + chunk) << 11) + (round << 8) + tid] = s;
          __syncthreads();
        }
      }
    }
  }
}

// ---------------- reduce: levels 0..5, sum per-chunk partials ----------------
__global__ __launch_bounds__(256)
void reduce_kernel(const float* __restrict__ part, float* __restrict__ t, LP P) {
  int b = blockIdx.x, l = 0, segs = 2;
  while (b >= segs) { b -= segs; l++; segs <<= 1; }   // l in 0..5
  const int nch = 32 >> l;
  const int tid = threadIdx.x;
  const float* src = part + ((size_t)(l * 64 + b * nch) << 11) + tid * 8;
  float4 a = make_float4(0.f, 0.f, 0.f, 0.f);
  float4 c = make_float4(0.f, 0.f, 0.f, 0.f);
  for (int k = 0; k < nch; k++) {
    float4 v0 = *(const float4*)&src[(size_t)k << 11];
    float4 v1 = *(const float4*)&src[((size_t)k << 11) + 4];
    a.x += v0.x; a.y += v0.y; a.z += v0.z; a.w += v0.w;
    c.x += v1.x; c.y += v1.y; c.z += v1.z; c.w += v1.w;
  }
  float* dst = t + P.t_off[l] + (b << 11) + tid * 8;
  *(float4*)dst = a;
  *(float4*)&dst[4] = c;
}

// ---------------- y-pass ----------------
// out[n][i] = leaf(i)·x + s2 * sum_l sum_j U_l[i][j] * t_l[sib][n][j]
// grid: 512 blocks * 256 threads; thread = one row i, acc[32 n] in regs.
// u read straight from global (line reuse across j); tt reads are full-wave
// LDS broadcasts (conflict-free by construction).
__global__ __launch_bounds__(256)
void ypass_kernel(const float* __restrict__ x, const float* __restrict__ leaf,
                  const float* __restrict__ scale, const float* __restrict__ t,
                  float* __restrict__ out, LP P) {
  __shared__ float smem[8192];
  const int tid = threadIdx.x;
  const int R0 = blockIdx.x << 8;
  const int i = R0 + tid;
  const float sc = scale[0];
  const float s2 = sc * sc;

  float acc[32];
  #pragma unroll
  for (int n = 0; n < 32; n++) acc[n] = 0.f;

  // ---- Phase A: leaf block-diagonal ----
  {
    // stage full 32 x 256 tile: thread (snn, sq) stages cols h*32 + sq*4, h=0..7
    // (each wave instruction: 8 rows x 128 B contiguous -> fully coalesced)
    const int snn = tid >> 3, sq = tid & 7;
    #pragma unroll
    for (int h = 0; h < 8; h++) {
      const int c = h * 32 + sq * 4;
      float4 v = *(const float4*)&x[snn * NN + R0 + c];
      *(float4*)&smem[snn * 256 + c] = v;
    }
    __syncthreads();
    const int cblk = (tid >> 5) << 5;
    const float* lrow = leaf + (size_t)(i >> 5) * 1024 + (i & 31) * 32;
    #pragma unroll
    for (int sq2 = 0; sq2 < 8; sq2++) {
      float4 lv = *(const float4*)&lrow[sq2 * 4];
      #pragma unroll
      for (int n = 0; n < 32; n++) {
        float4 xv = *(const float4*)&smem[n * 256 + cblk + sq2 * 4];
        acc[n] += lv.x * xv.x + lv.y * xv.y + lv.z * xv.z + lv.w * xv.w;
      }
    }
    __syncthreads();
  }

  // ---- Phase B: 12 levels ----
  for (int l = 0; l < 12; l++) {
    const int r = P.r[l], lb = P.lb[l];
    const float* tl = t + P.t_off[l];
    const int segf = 32 * r;
    const int K = (lb >= 8) ? 1 : (1 << (8 - lb));
    const int tot4 = (K * segf) >> 2;
    const int bseg = R0 >> lb;
    for (int idx4 = tid; idx4 < tot4; idx4 += 256) {
      int flat = idx4 << 2;
      int kk = flat / segf;
      int rem = flat - kk * segf;
      int sib = (bseg + kk) ^ 1;
      float4 v = *(const float4*)&tl[(size_t)sib * segf + rem];
      v.x *= s2; v.y *= s2; v.z *= s2; v.w *= s2;
      *(float4*)&smem[flat] = v;
    }
    __syncthreads();
    const int kk = tid >> lb;           // 0 when lb >= 8
    const float* tb = smem + kk * segf;
    const float* ur = P.u[l] + (size_t)i * r;
    for (int jq = 0; jq < (r >> 2); jq++) {
      float4 uvv = *(const float4*)&ur[jq * 4];
      #pragma unroll
      for (int n = 0; n < 32; n++) {
        float4 tv = *(const float4*)&tb[n * r + jq * 4];
        acc[n] += uvv.x * tv.x + uvv.y * tv.y + uvv.z * tv.z + uvv.w * tv.w;
      }
    }
    __syncthreads();
  }

  #pragma unroll
  for (int n = 0; n < 32; n++) out[(size_t)n * NN + i] = acc[n];
}

extern "C" void kernel_launch(void* const* d_in, const int* in_sizes, int n_in,
                              void* d_out, int out_size, void* d_ws, size_t ws_size,
                              hipStream_t stream) {
  const float* x     = (const float*)d_in[0];
  const float* leaf  = (const float*)d_in[1];
  const float* scale = (const float*)d_in[2];

  static const int RANKS[12] = {64,64,64,64,64,64,64,64,64,52,32,20};
  LP P;
  int off = 0;
  for (int l = 0; l < 12; l++) {
    P.u[l] = (const float*)d_in[3 + l];
    P.r[l] = RANKS[l];
    P.lb[l] = 16 - l;
    P.t_off[l] = off;
    off += (2 << l) * 32 * RANKS[l];
  }

  float* t = (float*)d_ws;
  float* part = t + off;   // 6 levels * 64 chunks * 2048 floats = 3 MB

  tpass_kernel<<<dim3(12 * 64), dim3(256), 0, stream>>>(x, t, part, P);
  reduce_kernel<<<dim3(126), dim3(256), 0, stream>>>(part, t, P);
  ypass_kernel<<<dim3(512), dim3(256), 0, stream>>>(x, leaf, scale, t,
                                                    (float*)d_out, P);
}